// Round 2
// baseline (2799.966 us; speedup 1.0000x reference)
//
#include <hip/hip_runtime.h>

#define NN 10000
#define EE 100000
#define LL 9
#define HH 8
#define NLC (NN*LL*64)

__device__ __forceinline__ float sigmoidf_(float x){ return 1.0f/(1.0f+__expf(-x)); }

// ============================ fast path ============================

// K1: xsrc = x@W_src (+b_src on l==0), xdst = x@W_dst. 16 rows/block, 4 rows/wave.
__global__ __launch_bounds__(256) void k_node_lin(
    const float* __restrict__ x, const float* __restrict__ Ws, const float* __restrict__ bs,
    const float* __restrict__ Wd, float* __restrict__ xs, float* __restrict__ xd)
{
  const int wid = threadIdx.x >> 6;
  const int c   = threadIdx.x & 63;
  const int base = blockIdx.x * 16;
  __shared__ float xr[16][64];
  for (int i = threadIdx.x; i < 1024; i += 256) xr[i>>6][i&63] = x[(size_t)base*64 + i];
  __syncthreads();
  float as[4] = {0.f,0.f,0.f,0.f};
  float ad[4] = {0.f,0.f,0.f,0.f};
  for (int kq = 0; kq < 16; kq++){
    const int k0 = kq*4;
    const float a0 = Ws[(k0+0)*64+c], a1 = Ws[(k0+1)*64+c], a2 = Ws[(k0+2)*64+c], a3 = Ws[(k0+3)*64+c];
    const float b0 = Wd[(k0+0)*64+c], b1 = Wd[(k0+1)*64+c], b2 = Wd[(k0+2)*64+c], b3 = Wd[(k0+3)*64+c];
    #pragma unroll
    for (int j = 0; j < 4; j++){
      const float4 xv = *(const float4*)&xr[wid*4+j][k0];
      as[j] += xv.x*a0 + xv.y*a1 + xv.z*a2 + xv.w*a3;
      ad[j] += xv.x*b0 + xv.y*b1 + xv.z*b2 + xv.w*b3;
    }
  }
  #pragma unroll
  for (int j = 0; j < 4; j++){
    const int row = base + wid*4 + j;
    float o = as[j];
    if (row % LL == 0) o += bs[c];
    xs[(size_t)row*64+c] = o;
    xd[(size_t)row*64+c] = ad[j];
  }
}

// K2: radial MLP -> wbuf (E x 576 f32). 16 edges/block, 4 edges/wave.
__global__ __launch_bounds__(256) void k_radial(
    const float* __restrict__ escal,
    const float* __restrict__ w1, const float* __restrict__ b1,
    const float* __restrict__ lnw, const float* __restrict__ lnb,
    const float* __restrict__ w2, const float* __restrict__ woff,
    float* __restrict__ wbuf)
{
  const int wid = threadIdx.x >> 6;
  const int c   = threadIdx.x & 63;
  const int base = blockIdx.x * 16;
  __shared__ float se[16][64];
  for (int i = threadIdx.x; i < 1024; i += 256) se[i>>6][i&63] = escal[(size_t)base*64 + i];
  __syncthreads();
  // layer 1
  const float bb = b1[c];
  float hh[4] = {bb, bb, bb, bb};
  for (int kq = 0; kq < 16; kq++){
    const int k0 = kq*4;
    const float a0 = w1[(k0+0)*64+c], a1 = w1[(k0+1)*64+c], a2 = w1[(k0+2)*64+c], a3 = w1[(k0+3)*64+c];
    #pragma unroll
    for (int j = 0; j < 4; j++){
      const float4 hv = *(const float4*)&se[wid*4+j][k0];
      hh[j] += hv.x*a0 + hv.y*a1 + hv.z*a2 + hv.w*a3;
    }
  }
  // LN + silu
  const float lw = lnw[c], lb = lnb[c];
  #pragma unroll
  for (int j = 0; j < 4; j++){
    const float v = hh[j];
    float s1 = v, s2 = v*v;
    #pragma unroll
    for (int m = 1; m < 64; m <<= 1){ s1 += __shfl_xor(s1, m, 64); s2 += __shfl_xor(s2, m, 64); }
    const float mean = s1 * (1.0f/64.0f);
    const float var  = s2 * (1.0f/64.0f) - mean*mean;
    const float g = (v - mean) * rsqrtf(var + 1e-5f) * lw + lb;
    hh[j] = g * sigmoidf_(g);
  }
  __syncthreads();
  #pragma unroll
  for (int j = 0; j < 4; j++) se[wid*4+j][c] = hh[j];
  __syncthreads();
  // w2 GEMM: out (e, r*64+c)
  for (int r = 0; r < 9; r++){
    float acc[4] = {0.f,0.f,0.f,0.f};
    const float off = woff[r*64+c];
    const float* wp = w2 + r*64 + c;
    for (int kq = 0; kq < 16; kq++){
      const int k0 = kq*4;
      const float a0 = wp[(size_t)(k0+0)*576], a1 = wp[(size_t)(k0+1)*576];
      const float a2 = wp[(size_t)(k0+2)*576], a3 = wp[(size_t)(k0+3)*576];
      #pragma unroll
      for (int j = 0; j < 4; j++){
        const float4 hv = *(const float4*)&se[wid*4+j][k0];
        acc[j] += hv.x*a0 + hv.y*a1 + hv.z*a2 + hv.w*a3;
      }
    }
    #pragma unroll
    for (int j = 0; j < 4; j++)
      wbuf[(size_t)(base + wid*4 + j)*576 + r*64 + c] = acc[j] + off;
  }
}

// K3: cp_tp1 (l=0 row) + alpha -> logits + segment max. 16 edges/block.
__global__ __launch_bounds__(256) void k_edge_a(
    const float* __restrict__ xsrc, const float* __restrict__ xdst,
    const float* __restrict__ eattr, const float* __restrict__ wbuf,
    const float* __restrict__ U1, const float* __restrict__ V1, const float* __restrict__ Y1,
    const float* __restrict__ Wa, const float* __restrict__ ba,
    const float* __restrict__ adot,
    const int* __restrict__ esrc, const int* __restrict__ edst,
    float* __restrict__ alog, unsigned int* __restrict__ amaxu)
{
  const int wid = threadIdx.x >> 6;
  const int c   = threadIdx.x & 63;
  const int base = blockIdx.x * 16;
  __shared__ float sV[81], sY[81], sU0[9];
  __shared__ float sh9[16][9];
  __shared__ float sm0[4][64];
  for (int i = threadIdx.x; i < 81; i += 256){ sV[i] = V1[i]; sY[i] = Y1[i]; }
  if (threadIdx.x < 9) sU0[threadIdx.x] = U1[threadIdx.x];
  for (int i = threadIdx.x; i < 144; i += 256) sh9[i/9][i%9] = eattr[(size_t)base*9 + i];
  __syncthreads();
  const float bac = ba[c];
  const float adc = adot[c];
  for (int j = 0; j < 4; j++){
    const int e  = base + wid*4 + j;
    const int er = wid*4 + j;
    const int src = esrc[e], dst = edst[e];
    const float* ps = xsrc + (size_t)src*576 + c;
    const float* pd = xdst + (size_t)dst*576 + c;
    float msg[9];
    #pragma unroll
    for (int l = 0; l < 9; l++) msg[l] = ps[l*64] + pd[l*64];
    const float* wp = wbuf + (size_t)e*576 + c;
    float m0 = 0.f;
    #pragma unroll
    for (int r = 0; r < 9; r++){
      float yv = 0.f, xv = 0.f;
      #pragma unroll
      for (int l = 0; l < 9; l++){ yv += sh9[er][l]*sY[l*9+r]; xv += msg[l]*sV[l*9+r]; }
      m0 += xv * yv * wp[r*64] * sU0[r];
    }
    sm0[wid][c] = m0;
    float av = bac;
    for (int kq = 0; kq < 16; kq++){
      const int k0 = kq*4;
      const float a0 = Wa[(k0+0)*64+c], a1 = Wa[(k0+1)*64+c], a2 = Wa[(k0+2)*64+c], a3 = Wa[(k0+3)*64+c];
      const float4 mv = *(const float4*)&sm0[wid][k0];
      av += mv.x*a0 + mv.y*a1 + mv.z*a2 + mv.w*a3;
    }
    const float sl = 0.2f*av + 0.8f*av*sigmoidf_(av);
    float t = sl * adc;
    t += __shfl_xor(t, 1, 64);
    t += __shfl_xor(t, 2, 64);
    t += __shfl_xor(t, 4, 64);
    if ((c & 7) == 0){
      const int k = c >> 3;
      alog[(size_t)e*8 + k] = t;
      unsigned u = __float_as_uint(t);
      u = (u & 0x80000000u) ? ~u : (u | 0x80000000u);
      atomicMax(&amaxu[dst*8 + k], u);
    }
  }
}

// K4: p = exp(a - amax[dst]); asum[dst] += p
__global__ __launch_bounds__(256) void k_softmax(
    const float* __restrict__ alog, const unsigned int* __restrict__ amaxu,
    const int* __restrict__ edst, float* __restrict__ p, float* __restrict__ asum)
{
  const int i = blockIdx.x*256 + threadIdx.x;
  const int e = i >> 3, k = i & 7;
  const int dst = edst[e];
  const unsigned u = amaxu[dst*8 + k];
  const unsigned ub = (u & 0x80000000u) ? (u & 0x7fffffffu) : ~u;
  const float mx = __uint_as_float(ub);
  const float pv = __expf(alog[i] - mx);
  p[i] = pv;
  atomicAdd(&asum[dst*8 + k], pv);
}

// K5: cp_tp1 full + value GEMM + gating + cp_tp2 + weighted scatter. 16 edges/block.
__global__ __launch_bounds__(256) void k_edge_b(
    const float* __restrict__ xsrc, const float* __restrict__ xdst,
    const float* __restrict__ eattr, const float* __restrict__ wbuf,
    const float* __restrict__ U1, const float* __restrict__ V1, const float* __restrict__ Y1,
    const float* __restrict__ U2, const float* __restrict__ V2, const float* __restrict__ Y2,
    const float* __restrict__ Wv, const float* __restrict__ bv,
    const int* __restrict__ esrc, const int* __restrict__ edst,
    const float* __restrict__ p, const float* __restrict__ asum,
    float* __restrict__ accum)
{
  const int wid = threadIdx.x >> 6;
  const int c   = threadIdx.x & 63;
  const int base = blockIdx.x * 16;
  __shared__ float sU1[81], sV1[81], sY1[81], sU2[81], sV2[81], sY2[81];
  __shared__ float sh9[16][9];
  __shared__ float ms[4][9][64];
  for (int i = threadIdx.x; i < 81; i += 256){
    sU1[i] = U1[i]; sV1[i] = V1[i]; sY1[i] = Y1[i];
    sU2[i] = U2[i]; sV2[i] = V2[i]; sY2[i] = Y2[i];
  }
  for (int i = threadIdx.x; i < 144; i += 256) sh9[i/9][i%9] = eattr[(size_t)base*9 + i];
  __syncthreads();
  const float bvc = bv[c], bgc = bv[64+c];
  for (int j = 0; j < 4; j++){
    const int e  = base + wid*4 + j;
    const int er = wid*4 + j;
    const int src = esrc[e], dst = edst[e];
    const float* ps = xsrc + (size_t)src*576 + c;
    const float* pd = xdst + (size_t)dst*576 + c;
    float msg[9];
    #pragma unroll
    for (int l = 0; l < 9; l++) msg[l] = ps[l*64] + pd[l*64];
    const float* wp = wbuf + (size_t)e*576 + c;
    // cp_tp1
    float tmp1[9];
    #pragma unroll
    for (int r = 0; r < 9; r++){
      float yv = 0.f, xv = 0.f;
      #pragma unroll
      for (int l = 0; l < 9; l++){ yv += sh9[er][l]*sY1[l*9+r]; xv += msg[l]*sV1[l*9+r]; }
      tmp1[r] = xv * yv * wp[r*64];
    }
    #pragma unroll
    for (int l = 0; l < 9; l++){
      float m2 = 0.f;
      #pragma unroll
      for (int r = 0; r < 9; r++) m2 += tmp1[r]*sU1[l*9+r];
      ms[wid][l][c] = m2;
    }
    __builtin_amdgcn_s_waitcnt(0); // ensure own-wave LDS writes visible (lgkmcnt 0)
    // value GEMM (val cols 0..63 for all l, gate cols 64..127 for l=0)
    float val[9];
    #pragma unroll
    for (int l = 0; l < 9; l++) val[l] = (l == 0) ? bvc : 0.f;
    float gt = bgc;
    for (int kq = 0; kq < 16; kq++){
      const int k0 = kq*4;
      const float w0 = Wv[(k0+0)*128+c],   w1 = Wv[(k0+1)*128+c],   w2 = Wv[(k0+2)*128+c],   w3 = Wv[(k0+3)*128+c];
      const float g0 = Wv[(k0+0)*128+64+c],g1 = Wv[(k0+1)*128+64+c],g2 = Wv[(k0+2)*128+64+c],g3 = Wv[(k0+3)*128+64+c];
      #pragma unroll
      for (int l = 0; l < 9; l++){
        const float4 mv = *(const float4*)&ms[wid][l][k0];
        val[l] += mv.x*w0 + mv.y*w1 + mv.z*w2 + mv.w*w3;
        if (l == 0) gt += mv.x*g0 + mv.y*g1 + mv.z*g2 + mv.w*g3;
      }
    }
    const float gs = sigmoidf_(gt);
    val[0] = val[0] * sigmoidf_(val[0]);
    #pragma unroll
    for (int l = 1; l < 9; l++) val[l] *= gs;
    // cp_tp2
    float tmp2[9];
    #pragma unroll
    for (int r = 0; r < 9; r++){
      float yv = 0.f, xv = 0.f;
      #pragma unroll
      for (int l = 0; l < 9; l++){ yv += sh9[er][l]*sY2[l*9+r]; xv += val[l]*sV2[l*9+r]; }
      tmp2[r] = xv * yv * wp[r*64];
    }
    const int hg = c >> 3;
    const float cf = p[(size_t)e*8 + hg] / (asum[dst*8 + hg] + 1e-16f);
    float* ap = accum + (size_t)dst*576 + c;
    #pragma unroll
    for (int l = 0; l < 9; l++){
      float o = 0.f;
      #pragma unroll
      for (int r = 0; r < 9; r++) o += tmp2[r]*sU2[l*9+r];
      atomicAdd(ap + l*64, o*cf);
    }
  }
}

// K6: out = accum @ W_proj (+b_proj on l==0). 16 rows/block.
__global__ __launch_bounds__(256) void k_proj(
    const float* __restrict__ acc, const float* __restrict__ Wp, const float* __restrict__ bp,
    float* __restrict__ out)
{
  const int wid = threadIdx.x >> 6;
  const int c   = threadIdx.x & 63;
  const int base = blockIdx.x * 16;
  __shared__ float xr[16][64];
  for (int i = threadIdx.x; i < 1024; i += 256) xr[i>>6][i&63] = acc[(size_t)base*64 + i];
  __syncthreads();
  float os[4] = {0.f,0.f,0.f,0.f};
  for (int kq = 0; kq < 16; kq++){
    const int k0 = kq*4;
    const float a0 = Wp[(k0+0)*64+c], a1 = Wp[(k0+1)*64+c], a2 = Wp[(k0+2)*64+c], a3 = Wp[(k0+3)*64+c];
    #pragma unroll
    for (int j = 0; j < 4; j++){
      const float4 xv = *(const float4*)&xr[wid*4+j][k0];
      os[j] += xv.x*a0 + xv.y*a1 + xv.z*a2 + xv.w*a3;
    }
  }
  #pragma unroll
  for (int j = 0; j < 4; j++){
    const int row = base + wid*4 + j;
    float o = os[j];
    if (row % LL == 0) o += bp[c];
    out[(size_t)row*64+c] = o;
  }
}

// ============================ fallback path (small ws): round-1 kernels ============================

__global__ __launch_bounds__(256) void k_edge_a_fb(
    const float* __restrict__ xsrc, const float* __restrict__ xdst,
    const float* __restrict__ eattr, const float* __restrict__ escal,
    const float* __restrict__ w1, const float* __restrict__ b1,
    const float* __restrict__ lnw, const float* __restrict__ lnb,
    const float* __restrict__ w2, const float* __restrict__ woff,
    const float* __restrict__ U1, const float* __restrict__ V1, const float* __restrict__ Y1,
    const float* __restrict__ Wa, const float* __restrict__ ba,
    const float* __restrict__ adot,
    const int* __restrict__ esrc, const int* __restrict__ edst,
    float* __restrict__ alog, unsigned int* __restrict__ amaxu)
{
  const int wid = threadIdx.x >> 6;
  const int c   = threadIdx.x & 63;
  const int e   = blockIdx.x*4 + wid;
  __shared__ float sbuf[4][64];
  __shared__ float sh9[4][9];
  __shared__ float sU1[81], sV1[81], sY1[81];
  __shared__ float m0s[4][64];
  const int src = esrc[e], dst = edst[e];
  sbuf[wid][c] = escal[e*64+c];
  if (c<9) sh9[wid][c] = eattr[e*9+c];
  for (int i=threadIdx.x; i<81; i+=256){ sU1[i]=U1[i]; sV1[i]=V1[i]; sY1[i]=Y1[i]; }
  __syncthreads();
  float hh = b1[c];
  #pragma unroll 8
  for (int k=0;k<64;k++) hh += sbuf[wid][k]*w1[k*64+c];
  float s = hh;
  #pragma unroll
  for (int m=1;m<64;m<<=1) s += __shfl_xor(s,m,64);
  const float mean = s*(1.0f/64.0f);
  const float dv = hh-mean;
  float q = dv*dv;
  #pragma unroll
  for (int m=1;m<64;m<<=1) q += __shfl_xor(q,m,64);
  const float inv = rsqrtf(q*(1.0f/64.0f)+1e-5f);
  const float g = dv*inv*lnw[c]+lnb[c];
  const float h2 = g*sigmoidf_(g);
  __syncthreads();
  sbuf[wid][c] = h2;
  __syncthreads();
  float msg[9];
  { const float* ps = xsrc + (size_t)src*576 + c;
    const float* pd = xdst + (size_t)dst*576 + c;
    #pragma unroll
    for (int l=0;l<9;l++) msg[l] = ps[l*64] + pd[l*64]; }
  float m0v = 0.f;
  #pragma unroll
  for (int r=0;r<9;r++){
    float wvv = woff[r*64+c];
    #pragma unroll 8
    for (int k=0;k<64;k++) wvv += sbuf[wid][k]*w2[k*576+r*64+c];
    float yv=0.f, xvv=0.f;
    #pragma unroll
    for (int l=0;l<9;l++){ yv += sh9[wid][l]*sY1[l*9+r]; xvv += msg[l]*sV1[l*9+r]; }
    m0v += xvv*yv*wvv*sU1[r];
  }
  m0s[wid][c] = m0v;
  __syncthreads();
  float av = ba[c];
  #pragma unroll 8
  for (int k=0;k<64;k++) av += m0s[wid][k]*Wa[k*64+c];
  const float sl = 0.2f*av + 0.8f*av*sigmoidf_(av);
  float t = sl*adot[c];
  t += __shfl_xor(t,1,64);
  t += __shfl_xor(t,2,64);
  t += __shfl_xor(t,4,64);
  if ((c&7)==0){
    const int k = c>>3;
    alog[e*8+k] = t;
    unsigned u = __float_as_uint(t);
    u = (u & 0x80000000u) ? ~u : (u | 0x80000000u);
    atomicMax(&amaxu[dst*8+k], u);
  }
}

__global__ __launch_bounds__(256) void k_edge_b_fb(
    const float* __restrict__ xsrc, const float* __restrict__ xdst,
    const float* __restrict__ eattr, const float* __restrict__ escal,
    const float* __restrict__ w1, const float* __restrict__ b1,
    const float* __restrict__ lnw, const float* __restrict__ lnb,
    const float* __restrict__ w2, const float* __restrict__ woff,
    const float* __restrict__ U1, const float* __restrict__ V1, const float* __restrict__ Y1,
    const float* __restrict__ U2, const float* __restrict__ V2, const float* __restrict__ Y2,
    const float* __restrict__ Wv, const float* __restrict__ bv,
    const int* __restrict__ esrc, const int* __restrict__ edst,
    const float* __restrict__ p, const float* __restrict__ asum,
    float* __restrict__ accum)
{
  const int wid = threadIdx.x >> 6;
  const int c   = threadIdx.x & 63;
  const int e   = blockIdx.x*4 + wid;
  __shared__ float sbuf[4][64];
  __shared__ float sh9[4][9];
  __shared__ float sU1[81], sV1[81], sY1[81];
  __shared__ float sU2[81], sV2[81], sY2[81];
  __shared__ float msl[4][9][64];
  __shared__ float cfs[4][8];
  const int src = esrc[e], dst = edst[e];
  sbuf[wid][c] = escal[e*64+c];
  if (c<9) sh9[wid][c] = eattr[e*9+c];
  for (int i=threadIdx.x; i<81; i+=256){
    sU1[i]=U1[i]; sV1[i]=V1[i]; sY1[i]=Y1[i];
    sU2[i]=U2[i]; sV2[i]=V2[i]; sY2[i]=Y2[i];
  }
  if (c<8) cfs[wid][c] = p[e*8+c] / (asum[dst*8+c] + 1e-16f);
  __syncthreads();
  float hh = b1[c];
  #pragma unroll 8
  for (int k=0;k<64;k++) hh += sbuf[wid][k]*w1[k*64+c];
  float s = hh;
  #pragma unroll
  for (int m=1;m<64;m<<=1) s += __shfl_xor(s,m,64);
  const float mean = s*(1.0f/64.0f);
  const float dv = hh-mean;
  float q = dv*dv;
  #pragma unroll
  for (int m=1;m<64;m<<=1) q += __shfl_xor(q,m,64);
  const float inv = rsqrtf(q*(1.0f/64.0f)+1e-5f);
  const float g = dv*inv*lnw[c]+lnb[c];
  const float h2 = g*sigmoidf_(g);
  __syncthreads();
  sbuf[wid][c] = h2;
  __syncthreads();
  float msg[9];
  { const float* ps = xsrc + (size_t)src*576 + c;
    const float* pd = xdst + (size_t)dst*576 + c;
    #pragma unroll
    for (int l=0;l<9;l++) msg[l] = ps[l*64] + pd[l*64]; }
  float wv[9], tmp1[9];
  #pragma unroll
  for (int r=0;r<9;r++){
    float t = woff[r*64+c];
    #pragma unroll 8
    for (int k=0;k<64;k++) t += sbuf[wid][k]*w2[k*576+r*64+c];
    wv[r] = t;
    float yv=0.f, xvv=0.f;
    #pragma unroll
    for (int l=0;l<9;l++){ yv += sh9[wid][l]*sY1[l*9+r]; xvv += msg[l]*sV1[l*9+r]; }
    tmp1[r] = xvv*yv*t;
  }
  #pragma unroll
  for (int l=0;l<9;l++){
    float m2 = 0.f;
    #pragma unroll
    for (int r=0;r<9;r++) m2 += tmp1[r]*sU1[l*9+r];
    msl[wid][l][c] = m2;
  }
  __syncthreads();
  float ga = bv[64+c];
  #pragma unroll 8
  for (int k=0;k<64;k++) ga += msl[wid][0][k]*Wv[k*128+64+c];
  const float gate = sigmoidf_(ga);
  float vvv[9];
  #pragma unroll
  for (int l=0;l<9;l++){
    float a = (l==0)? bv[c] : 0.0f;
    #pragma unroll 8
    for (int k=0;k<64;k++) a += msl[wid][l][k]*Wv[k*128+c];
    vvv[l]=a;
  }
  vvv[0] = vvv[0]*sigmoidf_(vvv[0]);
  #pragma unroll
  for (int l=1;l<9;l++) vvv[l] *= gate;
  float tmp2[9];
  #pragma unroll
  for (int r=0;r<9;r++){
    float yv=0.f, xvv=0.f;
    #pragma unroll
    for (int l=0;l<9;l++){ yv += sh9[wid][l]*sY2[l*9+r]; xvv += vvv[l]*sV2[l*9+r]; }
    tmp2[r] = xvv*yv*wv[r];
  }
  const float myc = cfs[wid][c>>3];
  float* ap = accum + (size_t)dst*576 + c;
  #pragma unroll
  for (int l=0;l<9;l++){
    float o = 0.f;
    #pragma unroll
    for (int r=0;r<9;r++) o += tmp2[r]*sU2[l*9+r];
    atomicAdd(ap + l*64, o*myc);
  }
}

// ============================ launch ============================

extern "C" void kernel_launch(void* const* d_in, const int* in_sizes, int n_in,
                              void* d_out, int out_size, void* d_ws, size_t ws_size,
                              hipStream_t stream)
{
  (void)in_sizes; (void)n_in; (void)out_size;
  const float* node_input = (const float*)d_in[0];
  const float* edge_attr  = (const float*)d_in[1];
  const float* edge_scal  = (const float*)d_in[2];
  const float* W_src   = (const float*)d_in[3];
  const float* b_src   = (const float*)d_in[4];
  const float* W_dst   = (const float*)d_in[5];
  const float* rad_w1  = (const float*)d_in[6];
  const float* rad_b1  = (const float*)d_in[7];
  const float* rad_ln_w= (const float*)d_in[8];
  const float* rad_ln_b= (const float*)d_in[9];
  const float* rad_w2  = (const float*)d_in[10];
  const float* rad_off = (const float*)d_in[11];
  const float* U1 = (const float*)d_in[12];
  const float* V1 = (const float*)d_in[13];
  const float* Y1 = (const float*)d_in[14];
  const float* U2 = (const float*)d_in[15];
  const float* V2 = (const float*)d_in[16];
  const float* Y2 = (const float*)d_in[17];
  const float* W_alpha = (const float*)d_in[18];
  const float* b_alpha = (const float*)d_in[19];
  const float* alpha_dot = (const float*)d_in[20];
  const float* W_value = (const float*)d_in[21];
  const float* b_value = (const float*)d_in[22];
  const float* W_proj  = (const float*)d_in[23];
  const float* b_proj  = (const float*)d_in[24];
  const int* esrc = (const int*)d_in[25];
  const int* edst = (const int*)d_in[26];

  float* xsrc  = (float*)d_ws;
  float* xdst  = xsrc + NLC;
  float* accum = xdst + NLC;
  float* alog  = accum + NLC;
  float* pbuf  = alog + (size_t)EE*HH;
  float* asum  = pbuf + (size_t)EE*HH;
  unsigned int* amaxu = (unsigned int*)(asum + (size_t)NN*HH);
  float* wbuf  = (float*)(amaxu + (size_t)NN*HH);

  const size_t need_small = ((size_t)3*NLC + 2ull*EE*HH + 2ull*NN*HH)*sizeof(float);
  const size_t need_full  = need_small + (size_t)EE*576*sizeof(float);
  if (ws_size < need_small) return;

  hipMemsetAsync(accum, 0, (size_t)NLC*sizeof(float), stream);
  hipMemsetAsync(asum, 0, (size_t)NN*HH*sizeof(float), stream);
  hipMemsetAsync(amaxu, 0, (size_t)NN*HH*sizeof(unsigned int), stream);

  k_node_lin<<<NN*LL/16, 256, 0, stream>>>(node_input, W_src, b_src, W_dst, xsrc, xdst);

  if (ws_size >= need_full){
    k_radial<<<EE/16, 256, 0, stream>>>(edge_scal, rad_w1, rad_b1, rad_ln_w, rad_ln_b,
                                        rad_w2, rad_off, wbuf);
    k_edge_a<<<EE/16, 256, 0, stream>>>(xsrc, xdst, edge_attr, wbuf,
        U1, V1, Y1, W_alpha, b_alpha, alpha_dot, esrc, edst, alog, amaxu);
    k_softmax<<<(EE*HH)/256, 256, 0, stream>>>(alog, amaxu, edst, pbuf, asum);
    k_edge_b<<<EE/16, 256, 0, stream>>>(xsrc, xdst, edge_attr, wbuf,
        U1, V1, Y1, U2, V2, Y2, W_value, b_value, esrc, edst, pbuf, asum, accum);
  } else {
    k_edge_a_fb<<<EE/4, 256, 0, stream>>>(xsrc, xdst, edge_attr, edge_scal,
        rad_w1, rad_b1, rad_ln_w, rad_ln_b, rad_w2, rad_off,
        U1, V1, Y1, W_alpha, b_alpha, alpha_dot, esrc, edst, alog, amaxu);
    k_softmax<<<(EE*HH)/256, 256, 0, stream>>>(alog, amaxu, edst, pbuf, asum);
    k_edge_b_fb<<<EE/4, 256, 0, stream>>>(xsrc, xdst, edge_attr, edge_scal,
        rad_w1, rad_b1, rad_ln_w, rad_ln_b, rad_w2, rad_off,
        U1, V1, Y1, U2, V2, Y2, W_value, b_value, esrc, edst, pbuf, asum, accum);
  }

  k_proj<<<NN*LL/16, 256, 0, stream>>>(accum, W_proj, b_proj, (float*)d_out);
}

// Round 3
// 1256.201 us; speedup vs baseline: 2.2289x; 2.2289x over previous
//
#include <hip/hip_runtime.h>

#define NN 10000
#define EE 100000
#define LL 9
#define HH 8
#define NLC (NN*LL*64)

__device__ __forceinline__ float sigmoidf_(float x){ return 1.0f/(1.0f+__expf(-x)); }

// K1: xsrc = x@W_src (+b_src on l==0), xdst = x@W_dst. 16 rows/block, 4 rows/wave.
__global__ __launch_bounds__(256) void k_node_lin(
    const float* __restrict__ x, const float* __restrict__ Ws, const float* __restrict__ bs,
    const float* __restrict__ Wd, float* __restrict__ xs, float* __restrict__ xd)
{
  const int wid = threadIdx.x >> 6;
  const int c   = threadIdx.x & 63;
  const int base = blockIdx.x * 16;
  __shared__ float xr[16][64];
  for (int i = threadIdx.x; i < 1024; i += 256) xr[i>>6][i&63] = x[(size_t)base*64 + i];
  __syncthreads();
  float as[4] = {0.f,0.f,0.f,0.f};
  float ad[4] = {0.f,0.f,0.f,0.f};
  for (int kq = 0; kq < 16; kq++){
    const int k0 = kq*4;
    const float a0 = Ws[(k0+0)*64+c], a1 = Ws[(k0+1)*64+c], a2 = Ws[(k0+2)*64+c], a3 = Ws[(k0+3)*64+c];
    const float b0 = Wd[(k0+0)*64+c], b1 = Wd[(k0+1)*64+c], b2 = Wd[(k0+2)*64+c], b3 = Wd[(k0+3)*64+c];
    #pragma unroll
    for (int j = 0; j < 4; j++){
      const float4 xv = *(const float4*)&xr[wid*4+j][k0];
      as[j] += xv.x*a0 + xv.y*a1 + xv.z*a2 + xv.w*a3;
      ad[j] += xv.x*b0 + xv.y*b1 + xv.z*b2 + xv.w*b3;
    }
  }
  #pragma unroll
  for (int j = 0; j < 4; j++){
    const int row = base + wid*4 + j;
    float o = as[j];
    if (row % LL == 0) o += bs[c];
    xs[(size_t)row*64+c] = o;
    xd[(size_t)row*64+c] = ad[j];
  }
}

// K2: fully fused edge pass. 16 edges/block, 4 edges/wave.
// radial MLP -> w ; gather msg ; cp_tp1 -> msg2(LDS) ; value+gate+alpha GEMMs ;
// activations ; logits -> pe=exp(a) (max-shift cancels in softmax ratio) ;
// cp_tp2 ; scatter: accum += pe*v, asum += pe.
__global__ __launch_bounds__(256) void k_edge_fused(
    const float* __restrict__ xsrc, const float* __restrict__ xdst,
    const float* __restrict__ eattr, const float* __restrict__ escal,
    const float* __restrict__ w1, const float* __restrict__ b1,
    const float* __restrict__ lnw, const float* __restrict__ lnb,
    const float* __restrict__ w2, const float* __restrict__ woff,
    const float* __restrict__ U1, const float* __restrict__ V1, const float* __restrict__ Y1,
    const float* __restrict__ U2, const float* __restrict__ V2, const float* __restrict__ Y2,
    const float* __restrict__ Wa, const float* __restrict__ ba, const float* __restrict__ adot,
    const float* __restrict__ Wv, const float* __restrict__ bv,
    const int* __restrict__ esrc, const int* __restrict__ edst,
    float* __restrict__ accum, float* __restrict__ asum)
{
  const int wid = threadIdx.x >> 6;
  const int c   = threadIdx.x & 63;
  const int base = blockIdx.x * 16;

  __shared__ float sU1[81], sV1[81], sU2[81], sV2[81];
  __shared__ float syv1[16][9], syv2[16][9];   // per-edge Y-contractions (uniform over c)
  __shared__ float se[16][64];                 // escal, then h
  __shared__ float ms[16][9][64];              // msg2 staging

  for (int i = threadIdx.x; i < 81; i += 256){
    sU1[i] = U1[i]; sV1[i] = V1[i]; sU2[i] = U2[i]; sV2[i] = V2[i];
  }
  if (threadIdx.x < 144){
    const int er = threadIdx.x / 9, r = threadIdx.x % 9;
    const float* ea = eattr + (size_t)(base + er)*9;
    float y1 = 0.f, y2 = 0.f;
    #pragma unroll
    for (int l = 0; l < 9; l++){ y1 += ea[l]*Y1[l*9+r]; y2 += ea[l]*Y2[l*9+r]; }
    syv1[er][r] = y1; syv2[er][r] = y2;
  }
  for (int i = threadIdx.x; i < 1024; i += 256) se[i>>6][i&63] = escal[(size_t)base*64 + i];
  __syncthreads();

  // ---- radial layer 1 + LN + silu ----
  const float bb = b1[c];
  float hh[4] = {bb, bb, bb, bb};
  for (int kq = 0; kq < 16; kq++){
    const int k0 = kq*4;
    const float a0 = w1[(k0+0)*64+c], a1 = w1[(k0+1)*64+c], a2 = w1[(k0+2)*64+c], a3 = w1[(k0+3)*64+c];
    #pragma unroll
    for (int j = 0; j < 4; j++){
      const float4 hv = *(const float4*)&se[wid*4+j][k0];
      hh[j] += hv.x*a0 + hv.y*a1 + hv.z*a2 + hv.w*a3;
    }
  }
  const float lw = lnw[c], lb = lnb[c];
  #pragma unroll
  for (int j = 0; j < 4; j++){
    const float v = hh[j];
    float s1 = v, s2 = v*v;
    #pragma unroll
    for (int m = 1; m < 64; m <<= 1){ s1 += __shfl_xor(s1, m, 64); s2 += __shfl_xor(s2, m, 64); }
    const float mean = s1 * (1.0f/64.0f);
    const float var  = s2 * (1.0f/64.0f) - mean*mean;
    const float g = (v - mean) * rsqrtf(var + 1e-5f) * lw + lb;
    hh[j] = g * sigmoidf_(g);
  }
  __syncthreads();
  #pragma unroll
  for (int j = 0; j < 4; j++) se[wid*4+j][c] = hh[j];
  __syncthreads();

  // ---- w2 GEMM: w[e][r][c] (kq outer, r inner: each weight load feeds 4 edges) ----
  float wv_[4][9];
  #pragma unroll
  for (int j = 0; j < 4; j++)
    #pragma unroll
    for (int r = 0; r < 9; r++) wv_[j][r] = 0.f;
  for (int kq = 0; kq < 16; kq++){
    const int k0 = kq*4;
    const float4 hv0 = *(const float4*)&se[wid*4+0][k0];
    const float4 hv1 = *(const float4*)&se[wid*4+1][k0];
    const float4 hv2 = *(const float4*)&se[wid*4+2][k0];
    const float4 hv3 = *(const float4*)&se[wid*4+3][k0];
    #pragma unroll
    for (int r = 0; r < 9; r++){
      const float* wp = w2 + (size_t)k0*576 + r*64 + c;
      const float a0 = wp[0], a1 = wp[576], a2 = wp[1152], a3 = wp[1728];
      wv_[0][r] += hv0.x*a0 + hv0.y*a1 + hv0.z*a2 + hv0.w*a3;
      wv_[1][r] += hv1.x*a0 + hv1.y*a1 + hv1.z*a2 + hv1.w*a3;
      wv_[2][r] += hv2.x*a0 + hv2.y*a1 + hv2.z*a2 + hv2.w*a3;
      wv_[3][r] += hv3.x*a0 + hv3.y*a1 + hv3.z*a2 + hv3.w*a3;
    }
  }
  #pragma unroll
  for (int j = 0; j < 4; j++)
    #pragma unroll
    for (int r = 0; r < 9; r++) wv_[j][r] += woff[r*64+c];

  // ---- gather + cp_tp1 -> msg2 into LDS ----
  int sdst[4];
  #pragma unroll
  for (int j = 0; j < 4; j++){
    const int er = wid*4 + j;
    const int e  = base + er;
    const int src = esrc[e], dst = edst[e];
    sdst[j] = dst;
    const float* ps = xsrc + (size_t)src*576 + c;
    const float* pd = xdst + (size_t)dst*576 + c;
    float msg[9];
    #pragma unroll
    for (int l = 0; l < 9; l++) msg[l] = ps[l*64] + pd[l*64];
    float tmp1[9];
    #pragma unroll
    for (int r = 0; r < 9; r++){
      float xv = 0.f;
      #pragma unroll
      for (int l = 0; l < 9; l++) xv += msg[l]*sV1[l*9+r];
      tmp1[r] = xv * syv1[er][r] * wv_[j][r];
    }
    #pragma unroll
    for (int l = 0; l < 9; l++){
      float m2 = 0.f;
      #pragma unroll
      for (int r = 0; r < 9; r++) m2 += tmp1[r]*sU1[l*9+r];
      ms[er][l][c] = m2;
    }
  }
  __syncthreads();

  // ---- value + gate + alpha GEMMs (kq outer; weight loads shared over 4 edges) ----
  const float bvc = bv[c], bgc = bv[64+c], bac = ba[c];
  float val[4][9], gt[4], av[4];
  #pragma unroll
  for (int j = 0; j < 4; j++){
    val[j][0] = bvc;
    #pragma unroll
    for (int l = 1; l < 9; l++) val[j][l] = 0.f;
    gt[j] = bgc; av[j] = bac;
  }
  for (int kq = 0; kq < 16; kq++){
    const int k0 = kq*4;
    const float* wvp = Wv + (size_t)k0*128 + c;
    const float v0 = wvp[0],  v1 = wvp[128], v2 = wvp[256], v3 = wvp[384];
    const float g0 = wvp[64], g1 = wvp[192], g2 = wvp[320], g3 = wvp[448];
    const float* wap = Wa + (size_t)k0*64 + c;
    const float a0 = wap[0], a1 = wap[64], a2 = wap[128], a3 = wap[192];
    #pragma unroll
    for (int j = 0; j < 4; j++){
      const int er = wid*4 + j;
      const float4 m0 = *(const float4*)&ms[er][0][k0];
      val[j][0] += m0.x*v0 + m0.y*v1 + m0.z*v2 + m0.w*v3;
      gt[j]     += m0.x*g0 + m0.y*g1 + m0.z*g2 + m0.w*g3;
      av[j]     += m0.x*a0 + m0.y*a1 + m0.z*a2 + m0.w*a3;
      #pragma unroll
      for (int l = 1; l < 9; l++){
        const float4 ml = *(const float4*)&ms[er][l][k0];
        val[j][l] += ml.x*v0 + ml.y*v1 + ml.z*v2 + ml.w*v3;
      }
    }
  }

  // ---- activations, logits, cp_tp2, scatter ----
  const float adc = adot[c];
  #pragma unroll
  for (int j = 0; j < 4; j++){
    const int er = wid*4 + j;
    const int dst = sdst[j];
    const float gs = sigmoidf_(gt[j]);
    const float v0s = val[j][0];
    val[j][0] = v0s * sigmoidf_(v0s);
    #pragma unroll
    for (int l = 1; l < 9; l++) val[j][l] *= gs;
    // smooth lrelu + head dot -> logit per 8-lane head group
    const float a = av[j];
    const float sl = 0.2f*a + 0.8f*a*sigmoidf_(a);
    float t = sl * adc;
    t += __shfl_xor(t, 1, 64);
    t += __shfl_xor(t, 2, 64);
    t += __shfl_xor(t, 4, 64);
    const float pe = __expf(t);            // unnormalized softmax weight (shift cancels)
    if ((c & 7) == 0) atomicAdd(&asum[(size_t)dst*8 + (c>>3)], pe);
    // cp_tp2
    float tmp2[9];
    #pragma unroll
    for (int r = 0; r < 9; r++){
      float xv = 0.f;
      #pragma unroll
      for (int l = 0; l < 9; l++) xv += val[j][l]*sV2[l*9+r];
      tmp2[r] = xv * syv2[er][r] * wv_[j][r];
    }
    float* ap = accum + (size_t)dst*576 + c;
    #pragma unroll
    for (int l = 0; l < 9; l++){
      float o = 0.f;
      #pragma unroll
      for (int r = 0; r < 9; r++) o += tmp2[r]*sU2[l*9+r];
      atomicAdd(ap + l*64, o*pe);
    }
  }
}

// K3: out = (accum / (asum+1e-16)) @ W_proj (+b_proj on l==0). 16 rows/block.
__global__ __launch_bounds__(256) void k_norm_proj(
    const float* __restrict__ acc, const float* __restrict__ asum,
    const float* __restrict__ Wp, const float* __restrict__ bp,
    float* __restrict__ out)
{
  const int wid = threadIdx.x >> 6;
  const int c   = threadIdx.x & 63;
  const int base = blockIdx.x * 16;
  __shared__ float xr[16][64];
  for (int i = threadIdx.x; i < 1024; i += 256){
    const int row  = base + (i>>6);
    const int node = row / 9;
    const int head = (i & 63) >> 3;
    xr[i>>6][i&63] = acc[(size_t)base*64 + i] / (asum[(size_t)node*8 + head] + 1e-16f);
  }
  __syncthreads();
  float os[4] = {0.f,0.f,0.f,0.f};
  for (int kq = 0; kq < 16; kq++){
    const int k0 = kq*4;
    const float a0 = Wp[(k0+0)*64+c], a1 = Wp[(k0+1)*64+c], a2 = Wp[(k0+2)*64+c], a3 = Wp[(k0+3)*64+c];
    #pragma unroll
    for (int j = 0; j < 4; j++){
      const float4 xv = *(const float4*)&xr[wid*4+j][k0];
      os[j] += xv.x*a0 + xv.y*a1 + xv.z*a2 + xv.w*a3;
    }
  }
  #pragma unroll
  for (int j = 0; j < 4; j++){
    const int row = base + wid*4 + j;
    float o = os[j];
    if (row % LL == 0) o += bp[c];
    out[(size_t)row*64+c] = o;
  }
}

extern "C" void kernel_launch(void* const* d_in, const int* in_sizes, int n_in,
                              void* d_out, int out_size, void* d_ws, size_t ws_size,
                              hipStream_t stream)
{
  (void)in_sizes; (void)n_in; (void)out_size;
  const float* node_input = (const float*)d_in[0];
  const float* edge_attr  = (const float*)d_in[1];
  const float* edge_scal  = (const float*)d_in[2];
  const float* W_src   = (const float*)d_in[3];
  const float* b_src   = (const float*)d_in[4];
  const float* W_dst   = (const float*)d_in[5];
  const float* rad_w1  = (const float*)d_in[6];
  const float* rad_b1  = (const float*)d_in[7];
  const float* rad_ln_w= (const float*)d_in[8];
  const float* rad_ln_b= (const float*)d_in[9];
  const float* rad_w2  = (const float*)d_in[10];
  const float* rad_off = (const float*)d_in[11];
  const float* U1 = (const float*)d_in[12];
  const float* V1 = (const float*)d_in[13];
  const float* Y1 = (const float*)d_in[14];
  const float* U2 = (const float*)d_in[15];
  const float* V2 = (const float*)d_in[16];
  const float* Y2 = (const float*)d_in[17];
  const float* W_alpha = (const float*)d_in[18];
  const float* b_alpha = (const float*)d_in[19];
  const float* alpha_dot = (const float*)d_in[20];
  const float* W_value = (const float*)d_in[21];
  const float* b_value = (const float*)d_in[22];
  const float* W_proj  = (const float*)d_in[23];
  const float* b_proj  = (const float*)d_in[24];
  const int* esrc = (const int*)d_in[25];
  const int* edst = (const int*)d_in[26];

  float* xsrc  = (float*)d_ws;
  float* xdst  = xsrc + NLC;
  float* accum = xdst + NLC;
  float* asum  = accum + NLC;
  const size_t need = ((size_t)3*NLC + (size_t)NN*HH) * sizeof(float);
  if (ws_size < need) return;

  hipMemsetAsync(accum, 0, (size_t)NLC*sizeof(float), stream);
  hipMemsetAsync(asum, 0, (size_t)NN*HH*sizeof(float), stream);

  k_node_lin<<<NN*LL/16, 256, 0, stream>>>(node_input, W_src, b_src, W_dst, xsrc, xdst);
  k_edge_fused<<<EE/16, 256, 0, stream>>>(xsrc, xdst, edge_attr, edge_scal,
      rad_w1, rad_b1, rad_ln_w, rad_ln_b, rad_w2, rad_off,
      U1, V1, Y1, U2, V2, Y2,
      W_alpha, b_alpha, alpha_dot, W_value, b_value,
      esrc, edst, accum, asum);
  k_norm_proj<<<NN*LL/16, 256, 0, stream>>>(accum, asum, W_proj, b_proj, (float*)d_out);
}

// Round 4
// 1039.309 us; speedup vs baseline: 2.6941x; 1.2087x over previous
//
#include <hip/hip_runtime.h>

#define NN 10000
#define EE 100000
#define LL 9
#define HH 8
#define NLC (NN*LL*64)

__device__ __forceinline__ float sigmoidf_(float x){ return 1.0f/(1.0f+__expf(-x)); }

// K1: xsrc = x@W_src (+b_src on l==0), xdst = x@W_dst. 16 rows/block, 4 rows/wave.
__global__ __launch_bounds__(256) void k_node_lin(
    const float* __restrict__ x, const float* __restrict__ Ws, const float* __restrict__ bs,
    const float* __restrict__ Wd, float* __restrict__ xs, float* __restrict__ xd)
{
  const int wid = threadIdx.x >> 6;
  const int c   = threadIdx.x & 63;
  const int base = blockIdx.x * 16;
  __shared__ float xr[16][64];
  for (int i = threadIdx.x; i < 1024; i += 256) xr[i>>6][i&63] = x[(size_t)base*64 + i];
  __syncthreads();
  float as[4] = {0.f,0.f,0.f,0.f};
  float ad[4] = {0.f,0.f,0.f,0.f};
  for (int kq = 0; kq < 16; kq++){
    const int k0 = kq*4;
    const float a0 = Ws[(k0+0)*64+c], a1 = Ws[(k0+1)*64+c], a2 = Ws[(k0+2)*64+c], a3 = Ws[(k0+3)*64+c];
    const float b0 = Wd[(k0+0)*64+c], b1 = Wd[(k0+1)*64+c], b2 = Wd[(k0+2)*64+c], b3 = Wd[(k0+3)*64+c];
    #pragma unroll
    for (int j = 0; j < 4; j++){
      const float4 xv = *(const float4*)&xr[wid*4+j][k0];
      as[j] += xv.x*a0 + xv.y*a1 + xv.z*a2 + xv.w*a3;
      ad[j] += xv.x*b0 + xv.y*b1 + xv.z*b2 + xv.w*b3;
    }
  }
  #pragma unroll
  for (int j = 0; j < 4; j++){
    const int row = base + wid*4 + j;
    float o = as[j];
    if (row % LL == 0) o += bs[c];
    xs[(size_t)row*64+c] = o;
    xd[(size_t)row*64+c] = ad[j];
  }
}

// K2: fused edge pass. 512 threads = 8 waves, 16 edges/block, 2 edges/wave.
// __launch_bounds__(512,4): cap VGPR at 128 -> 4 waves/SIMD.
__global__ __launch_bounds__(512, 4) void k_edge_fused(
    const float* __restrict__ xsrc, const float* __restrict__ xdst,
    const float* __restrict__ eattr, const float* __restrict__ escal,
    const float* __restrict__ w1, const float* __restrict__ b1,
    const float* __restrict__ lnw, const float* __restrict__ lnb,
    const float* __restrict__ w2, const float* __restrict__ woff,
    const float* __restrict__ U1, const float* __restrict__ V1, const float* __restrict__ Y1,
    const float* __restrict__ U2, const float* __restrict__ V2, const float* __restrict__ Y2,
    const float* __restrict__ Wa, const float* __restrict__ ba, const float* __restrict__ adot,
    const float* __restrict__ Wv, const float* __restrict__ bv,
    const int* __restrict__ esrc, const int* __restrict__ edst,
    float* __restrict__ accum, float* __restrict__ asum)
{
  const int wid = threadIdx.x >> 6;   // 0..7
  const int c   = threadIdx.x & 63;
  const int base = blockIdx.x * 16;

  __shared__ float sU1[81], sV1[81], sU2[81], sV2[81];
  __shared__ float syv1[16][9], syv2[16][9];
  __shared__ float se[16][64];        // escal, then h
  __shared__ float ms[16][9][64];     // msg2 staging
  __shared__ float sw2[4*576];        // w2 kq-slice

  for (int i = threadIdx.x; i < 81; i += 512){
    sU1[i] = U1[i]; sV1[i] = V1[i]; sU2[i] = U2[i]; sV2[i] = V2[i];
  }
  if (threadIdx.x < 144){
    const int er = threadIdx.x / 9, r = threadIdx.x % 9;
    const float* ea = eattr + (size_t)(base + er)*9;
    float y1 = 0.f, y2 = 0.f;
    #pragma unroll
    for (int l = 0; l < 9; l++){ y1 += ea[l]*Y1[l*9+r]; y2 += ea[l]*Y2[l*9+r]; }
    syv1[er][r] = y1; syv2[er][r] = y2;
  }
  for (int i = threadIdx.x; i < 1024; i += 512) se[i>>6][i&63] = escal[(size_t)base*64 + i];
  __syncthreads();

  // ---- radial layer 1 + LN + silu (2 edges/wave) ----
  const float bb = b1[c];
  float hh[2] = {bb, bb};
  for (int kq = 0; kq < 16; kq++){
    const int k0 = kq*4;
    const float a0 = w1[(k0+0)*64+c], a1 = w1[(k0+1)*64+c], a2 = w1[(k0+2)*64+c], a3 = w1[(k0+3)*64+c];
    #pragma unroll
    for (int j = 0; j < 2; j++){
      const float4 hv = *(const float4*)&se[wid*2+j][k0];
      hh[j] += hv.x*a0 + hv.y*a1 + hv.z*a2 + hv.w*a3;
    }
  }
  const float lw = lnw[c], lb = lnb[c];
  #pragma unroll
  for (int j = 0; j < 2; j++){
    const float v = hh[j];
    float s1 = v, s2 = v*v;
    #pragma unroll
    for (int m = 1; m < 64; m <<= 1){ s1 += __shfl_xor(s1, m, 64); s2 += __shfl_xor(s2, m, 64); }
    const float mean = s1 * (1.0f/64.0f);
    const float var  = s2 * (1.0f/64.0f) - mean*mean;
    const float g = (v - mean) * rsqrtf(var + 1e-5f) * lw + lb;
    hh[j] = g * sigmoidf_(g);
  }
  __syncthreads();
  #pragma unroll
  for (int j = 0; j < 2; j++) se[wid*2+j][c] = hh[j];

  // ---- w2 GEMM with block-staged kq-slices of w2 (each slice fetched once per block) ----
  float wv_[2][9];
  #pragma unroll
  for (int j = 0; j < 2; j++)
    #pragma unroll
    for (int r = 0; r < 9; r++) wv_[j][r] = 0.f;
  for (int kq = 0; kq < 16; kq++){
    const int k0 = kq*4;
    __syncthreads();   // protect sw2 (and first iter: h stores to se)
    for (int i = threadIdx.x; i < 576; i += 512)
      ((float4*)sw2)[i] = ((const float4*)(w2 + (size_t)k0*576))[i];
    __syncthreads();
    const float4 hv0 = *(const float4*)&se[wid*2+0][k0];
    const float4 hv1 = *(const float4*)&se[wid*2+1][k0];
    #pragma unroll
    for (int r = 0; r < 9; r++){
      const float* wp = sw2 + r*64 + c;
      const float a0 = wp[0], a1 = wp[576], a2 = wp[1152], a3 = wp[1728];
      wv_[0][r] += hv0.x*a0 + hv0.y*a1 + hv0.z*a2 + hv0.w*a3;
      wv_[1][r] += hv1.x*a0 + hv1.y*a1 + hv1.z*a2 + hv1.w*a3;
    }
  }
  #pragma unroll
  for (int j = 0; j < 2; j++)
    #pragma unroll
    for (int r = 0; r < 9; r++) wv_[j][r] += woff[r*64+c];

  // ---- gather + cp_tp1 -> msg2 into LDS ----
  int sdst[2];
  #pragma unroll
  for (int j = 0; j < 2; j++){
    const int er = wid*2 + j;
    const int e  = base + er;
    const int src = esrc[e], dst = edst[e];
    sdst[j] = dst;
    const float* ps = xsrc + (size_t)src*576 + c;
    const float* pd = xdst + (size_t)dst*576 + c;
    float msg[9];
    #pragma unroll
    for (int l = 0; l < 9; l++) msg[l] = ps[l*64] + pd[l*64];
    float tmp1[9];
    #pragma unroll
    for (int r = 0; r < 9; r++){
      float xv = 0.f;
      #pragma unroll
      for (int l = 0; l < 9; l++) xv += msg[l]*sV1[l*9+r];
      tmp1[r] = xv * syv1[er][r] * wv_[j][r];
    }
    #pragma unroll
    for (int l = 0; l < 9; l++){
      float m2 = 0.f;
      #pragma unroll
      for (int r = 0; r < 9; r++) m2 += tmp1[r]*sU1[l*9+r];
      ms[er][l][c] = m2;
    }
  }
  __syncthreads();

  // ---- value + gate + alpha GEMMs ----
  const float bvc = bv[c], bgc = bv[64+c], bac = ba[c];
  float val[2][9], gt[2], av[2];
  #pragma unroll
  for (int j = 0; j < 2; j++){
    val[j][0] = bvc;
    #pragma unroll
    for (int l = 1; l < 9; l++) val[j][l] = 0.f;
    gt[j] = bgc; av[j] = bac;
  }
  for (int kq = 0; kq < 16; kq++){
    const int k0 = kq*4;
    const float* wvp = Wv + (size_t)k0*128 + c;
    const float v0 = wvp[0],  v1 = wvp[128], v2 = wvp[256], v3 = wvp[384];
    const float g0 = wvp[64], g1 = wvp[192], g2 = wvp[320], g3 = wvp[448];
    const float* wap = Wa + (size_t)k0*64 + c;
    const float a0 = wap[0], a1 = wap[64], a2 = wap[128], a3 = wap[192];
    #pragma unroll
    for (int j = 0; j < 2; j++){
      const int er = wid*2 + j;
      const float4 m0 = *(const float4*)&ms[er][0][k0];
      val[j][0] += m0.x*v0 + m0.y*v1 + m0.z*v2 + m0.w*v3;
      gt[j]     += m0.x*g0 + m0.y*g1 + m0.z*g2 + m0.w*g3;
      av[j]     += m0.x*a0 + m0.y*a1 + m0.z*a2 + m0.w*a3;
      #pragma unroll
      for (int l = 1; l < 9; l++){
        const float4 ml = *(const float4*)&ms[er][l][k0];
        val[j][l] += ml.x*v0 + ml.y*v1 + ml.z*v2 + ml.w*v3;
      }
    }
  }

  // ---- activations, logits, cp_tp2, scatter ----
  const float adc = adot[c];
  #pragma unroll
  for (int j = 0; j < 2; j++){
    const int er = wid*2 + j;
    const int dst = sdst[j];
    const float gs = sigmoidf_(gt[j]);
    const float v0s = val[j][0];
    val[j][0] = v0s * sigmoidf_(v0s);
    #pragma unroll
    for (int l = 1; l < 9; l++) val[j][l] *= gs;
    const float a = av[j];
    const float sl = 0.2f*a + 0.8f*a*sigmoidf_(a);
    float t = sl * adc;
    t += __shfl_xor(t, 1, 64);
    t += __shfl_xor(t, 2, 64);
    t += __shfl_xor(t, 4, 64);
    const float pe = __expf(t);            // unnormalized softmax weight (max-shift cancels)
    if ((c & 7) == 0) atomicAdd(&asum[(size_t)dst*8 + (c>>3)], pe);
    float tmp2[9];
    #pragma unroll
    for (int r = 0; r < 9; r++){
      float xv = 0.f;
      #pragma unroll
      for (int l = 0; l < 9; l++) xv += val[j][l]*sV2[l*9+r];
      tmp2[r] = xv * syv2[er][r] * wv_[j][r];
    }
    float* ap = accum + (size_t)dst*576 + c;
    #pragma unroll
    for (int l = 0; l < 9; l++){
      float o = 0.f;
      #pragma unroll
      for (int r = 0; r < 9; r++) o += tmp2[r]*sU2[l*9+r];
      atomicAdd(ap + l*64, o*pe);
    }
  }
}

// K3: out = (accum / (asum+1e-16)) @ W_proj (+b_proj on l==0). 16 rows/block.
__global__ __launch_bounds__(256) void k_norm_proj(
    const float* __restrict__ acc, const float* __restrict__ asum,
    const float* __restrict__ Wp, const float* __restrict__ bp,
    float* __restrict__ out)
{
  const int wid = threadIdx.x >> 6;
  const int c   = threadIdx.x & 63;
  const int base = blockIdx.x * 16;
  __shared__ float xr[16][64];
  for (int i = threadIdx.x; i < 1024; i += 256){
    const int row  = base + (i>>6);
    const int node = row / 9;
    const int head = (i & 63) >> 3;
    xr[i>>6][i&63] = acc[(size_t)base*64 + i] / (asum[(size_t)node*8 + head] + 1e-16f);
  }
  __syncthreads();
  float os[4] = {0.f,0.f,0.f,0.f};
  for (int kq = 0; kq < 16; kq++){
    const int k0 = kq*4;
    const float a0 = Wp[(k0+0)*64+c], a1 = Wp[(k0+1)*64+c], a2 = Wp[(k0+2)*64+c], a3 = Wp[(k0+3)*64+c];
    #pragma unroll
    for (int j = 0; j < 4; j++){
      const float4 xv = *(const float4*)&xr[wid*4+j][k0];
      os[j] += xv.x*a0 + xv.y*a1 + xv.z*a2 + xv.w*a3;
    }
  }
  #pragma unroll
  for (int j = 0; j < 4; j++){
    const int row = base + wid*4 + j;
    float o = os[j];
    if (row % LL == 0) o += bp[c];
    out[(size_t)row*64+c] = o;
  }
}

extern "C" void kernel_launch(void* const* d_in, const int* in_sizes, int n_in,
                              void* d_out, int out_size, void* d_ws, size_t ws_size,
                              hipStream_t stream)
{
  (void)in_sizes; (void)n_in; (void)out_size;
  const float* node_input = (const float*)d_in[0];
  const float* edge_attr  = (const float*)d_in[1];
  const float* edge_scal  = (const float*)d_in[2];
  const float* W_src   = (const float*)d_in[3];
  const float* b_src   = (const float*)d_in[4];
  const float* W_dst   = (const float*)d_in[5];
  const float* rad_w1  = (const float*)d_in[6];
  const float* rad_b1  = (const float*)d_in[7];
  const float* rad_ln_w= (const float*)d_in[8];
  const float* rad_ln_b= (const float*)d_in[9];
  const float* rad_w2  = (const float*)d_in[10];
  const float* rad_off = (const float*)d_in[11];
  const float* U1 = (const float*)d_in[12];
  const float* V1 = (const float*)d_in[13];
  const float* Y1 = (const float*)d_in[14];
  const float* U2 = (const float*)d_in[15];
  const float* V2 = (const float*)d_in[16];
  const float* Y2 = (const float*)d_in[17];
  const float* W_alpha = (const float*)d_in[18];
  const float* b_alpha = (const float*)d_in[19];
  const float* alpha_dot = (const float*)d_in[20];
  const float* W_value = (const float*)d_in[21];
  const float* b_value = (const float*)d_in[22];
  const float* W_proj  = (const float*)d_in[23];
  const float* b_proj  = (const float*)d_in[24];
  const int* esrc = (const int*)d_in[25];
  const int* edst = (const int*)d_in[26];

  float* xsrc  = (float*)d_ws;
  float* xdst  = xsrc + NLC;
  float* accum = xdst + NLC;
  float* asum  = accum + NLC;
  const size_t need = ((size_t)3*NLC + (size_t)NN*HH) * sizeof(float);
  if (ws_size < need) return;

  hipMemsetAsync(accum, 0, (size_t)NLC*sizeof(float), stream);
  hipMemsetAsync(asum, 0, (size_t)NN*HH*sizeof(float), stream);

  k_node_lin<<<NN*LL/16, 256, 0, stream>>>(node_input, W_src, b_src, W_dst, xsrc, xdst);
  k_edge_fused<<<EE/16, 512, 0, stream>>>(xsrc, xdst, edge_attr, edge_scal,
      rad_w1, rad_b1, rad_ln_w, rad_ln_b, rad_w2, rad_off,
      U1, V1, Y1, U2, V2, Y2,
      W_alpha, b_alpha, alpha_dot, W_value, b_value,
      esrc, edst, accum, asum);
  k_norm_proj<<<NN*LL/16, 256, 0, stream>>>(accum, asum, W_proj, b_proj, (float*)d_out);
}